// Round 18
// baseline (240.405 us; speedup 1.0000x reference)
//
#include <hip/hip_runtime.h>

#define B_ 256
#define T_ 512
#define I_ 256
#define H_ 256
#define CHUNK 64

typedef float    f32x4 __attribute__((ext_vector_type(4)));
typedef int      i32x4 __attribute__((ext_vector_type(4)));
typedef _Float16 f16x2 __attribute__((ext_vector_type(2)));
typedef _Float16 f16x4 __attribute__((ext_vector_type(4)));
typedef _Float16 f16x8 __attribute__((ext_vector_type(8)));

static __device__ __forceinline__ f16x8 cvt8(f32x4 a, f32x4 b) {
  return f16x8{(_Float16)a[0], (_Float16)a[1], (_Float16)a[2], (_Float16)a[3],
               (_Float16)b[0], (_Float16)b[1], (_Float16)b[2], (_Float16)b[3]};
}

// ---------------- fused RNN v13: i8 recurrence + tail-scheduled step body ----------------
// r17: step = ~404cyc issue + ~650cyc serial tail (MFMA lat -> reduce -> tanh -> quant
// -> LDS write -> barrier -> 120cyc ds_read). v13 reorders the step body:
//  (0) sx ds_read, (1) 4x qa ds_read_b128 issued FIRST after barrier,
//  (2) flush global-store + (3) background MFMA ride under qa latency,
//  (4) 8 INDEPENDENT i8 MFMAs (chain depth 2->1; i32 adds exact => absmax must be
//      bit-identical 0.01074219), (5) h-quant LDS write BEFORE outs write.
__global__ __launch_bounds__(512) void rnn_fused(const float* __restrict__ x,
                                                 const float* __restrict__ wxf,
                                                 const float* __restrict__ whf,
                                                 const float* __restrict__ bias_g,
                                                 float* __restrict__ io) {
  __shared__ __align__(16) _Float16 xpsA[CHUNK][H_];  // 32KB
  __shared__ __align__(16) _Float16 xpsB[CHUNK][H_];  // 32KB
  __shared__ __align__(16) _Float16 outs[CHUNK][H_];  // 32KB
  __shared__ __align__(16) char     sx[32768];        // 32KB swizzled x[64][256] f16
  __shared__ __align__(16) char     qhb[2][H_];       // 512B h state i8, dbuf

  const int tid = threadIdx.x;
  const int l   = tid & 63;
  const int w   = tid >> 6;
  const int lr  = l & 15;
  const int g   = l >> 4;
  const int h0  = w * 32;
  const size_t base = (size_t)blockIdx.x * (size_t)(T_ * H_);

  // stationary W_x f16 frags (64 VGPR) + W_h i8 frags (32 VGPR)
  f16x8 xB[16];
  i32x4 wQ[8];                                        // [tile*4 + ks]
#pragma unroll
  for (int tile = 0; tile < 2; ++tile) {
#pragma unroll
    for (int kc = 0; kc < 8; ++kc) {
      const float* px = wxf + (size_t)(h0 + tile * 16 + lr) * I_ + kc * 32 + g * 8;
      xB[tile * 8 + kc] = cvt8(*(const f32x4*)px, *(const f32x4*)(px + 4));
    }
#pragma unroll
    for (int ks = 0; ks < 4; ++ks) {
      const float* ph = whf + (size_t)(h0 + tile * 16 + lr) * H_ + ks * 64 + g * 16;
      i32x4 q;
#pragma unroll
      for (int w4 = 0; w4 < 4; ++w4) {
        f32x4 vv = *(const f32x4*)(ph + w4 * 4);
        int word = 0;
#pragma unroll
        for (int j = 0; j < 4; ++j) {
          float sq = fminf(fmaxf(vv[j] * 2032.f, -127.f), 127.f);
          word |= (((int)rintf(sq)) & 255) << (8 * j);
        }
        q[w4] = word;
      }
      wQ[tile * 4 + ks] = q;
    }
  }
  const float bias0 = bias_g[h0 + lr];
  const float bias1 = bias_g[h0 + 16 + lr];
  if (tid < 128) ((int*)qhb)[tid] = 0;

  const f32x4 z4 = f32x4{0.f, 0.f, 0.f, 0.f};
  const i32x4 zi = i32x4{0, 0, 0, 0};
  const float SCL = 1.f / 258064.f;                   // 1/(2032*127)
  const int swzr = (lr & 7) << 4;

  // ---- prologue: stage x[chunk 0] ----
  {
    const f32x4* src = (const f32x4*)(x + base);
#pragma unroll
    for (int j = 0; j < 4; ++j) {
      const int ebase = j * 4096 + tid * 8;
      f32x4 p0 = src[j * 1024 + tid * 2];
      f32x4 p1 = src[j * 1024 + tid * 2 + 1];
      const int row = ebase >> 8;
      const int boff = ((ebase & 255) * 2) ^ ((row & 7) << 4);
      *(f16x8*)(sx + row * 512 + boff) = cvt8(p0, p1);
    }
  }
  __syncthreads();
  // ---- prologue: full phase-1b -> xpsA ----
#pragma unroll 1
  for (int tt = 0; tt < 4; ++tt) {
    f32x4 aE0 = z4, aO0 = z4, aE1 = z4, aO1 = z4;
    const char* rowp = sx + (tt * 16 + lr) * 512;
#pragma unroll
    for (int kc = 0; kc < 8; kc += 2) {
      f16x8 a0 = *(const f16x8*)(rowp + ((kc * 64 + g * 16) ^ swzr));
      f16x8 a1 = *(const f16x8*)(rowp + (((kc + 1) * 64 + g * 16) ^ swzr));
      aE0 = __builtin_amdgcn_mfma_f32_16x16x32_f16(a0, xB[kc],         aE0, 0, 0, 0);
      aE1 = __builtin_amdgcn_mfma_f32_16x16x32_f16(a0, xB[8 + kc],     aE1, 0, 0, 0);
      aO0 = __builtin_amdgcn_mfma_f32_16x16x32_f16(a1, xB[kc + 1],     aO0, 0, 0, 0);
      aO1 = __builtin_amdgcn_mfma_f32_16x16x32_f16(a1, xB[8 + kc + 1], aO1, 0, 0, 0);
    }
    f32x4 y0 = aE0 + aO0, y1 = aE1 + aO1;
#pragma unroll
    for (int r = 0; r < 4; ++r) {
      xpsA[tt * 16 + g * 4 + r][h0 + lr]      = (_Float16)(y0[r] + bias0);
      xpsA[tt * 16 + g * 4 + r][h0 + 16 + lr] = (_Float16)(y1[r] + bias1);
    }
  }
  __syncthreads();

  // ---- main chunk loop ----
#pragma unroll 1
  for (int c = 0; c < 8; ++c) {
    const int t0 = c * CHUNK;
    _Float16 (*xpc)[H_] = (c & 1) ? xpsB : xpsA;
    _Float16 (*xpn)[H_] = (c & 1) ? xpsA : xpsB;
    const bool havenext = (c < 7);
    const int tprev = t0 - CHUNK;

    // phase 1a: stage x[c+1]
    if (havenext) {
      const f32x4* src = (const f32x4*)(x + base + (size_t)(t0 + CHUNK) * I_);
#pragma unroll
      for (int j = 0; j < 4; ++j) {
        const int ebase = j * 4096 + tid * 8;
        f32x4 p0 = src[j * 1024 + tid * 2];
        f32x4 p1 = src[j * 1024 + tid * 2 + 1];
        const int row = ebase >> 8;
        const int boff = ((ebase & 255) * 2) ^ ((row & 7) << 4);
        *(f16x8*)(sx + row * 512 + boff) = cvt8(p0, p1);
      }
    }
    __syncthreads();

    // pre-loop flush slot: prev chunk's row 0
    if (c > 0 && tid < 64) {
      f16x4 v = *(const f16x4*)&outs[0][tid * 4];
      *(f32x4*)(io + base + (size_t)tprev * H_ + tid * 4) =
          f32x4{(float)v[0], (float)v[1], (float)v[2], (float)v[3]};
    }
    __syncthreads();

    // 64 steps, 8 groups of 8; unroll 2 keeps mt/xB indices static
#pragma unroll 2
    for (int sb = 0; sb < 8; ++sb) {
      const int tt = sb >> 1;
      const int mt = sb & 1;
      f32x4 pacc = z4;
#pragma unroll
      for (int si = 0; si < 8; ++si) {
        const int s = sb * 8 + si;

        // (0) background A-frag LDS read issued first
        f16x8 abg;
        if (havenext) {
          const char* rowp = sx + (tt * 16 + lr) * 512;
          abg = *(const f16x8*)(rowp + ((si * 64 + g * 16) ^ swzr));
        }
        // (1) h-state reads — critical-path consumers come last
        const i32x4* qp = (const i32x4*)qhb[s & 1];
        i32x4 qa0 = qp[0 * 4 + g];
        i32x4 qa1 = qp[1 * 4 + g];
        i32x4 qa2 = qp[2 * 4 + g];
        i32x4 qa3 = qp[3 * 4 + g];

        // (2) flush slice: prev chunk row s+1 (global store, no LDS dep)
        if (c > 0 && s < 63 && tid < 64) {
          f16x4 v = *(const f16x4*)&outs[s + 1][tid * 4];
          *(f32x4*)(io + base + (size_t)(tprev + s + 1) * H_ + tid * 4) =
              f32x4{(float)v[0], (float)v[1], (float)v[2], (float)v[3]};
        }

        // (3) background xproj MFMA (waits only on its own sx read)
        if (havenext) {
          if (mt == 0)
            pacc = __builtin_amdgcn_mfma_f32_16x16x32_f16(abg, xB[si],     pacc, 0, 0, 0);
          else
            pacc = __builtin_amdgcn_mfma_f32_16x16x32_f16(abg, xB[8 + si], pacc, 0, 0, 0);
        }

        // (4) xp reads + 8 INDEPENDENT recurrence MFMAs (depth 1)
        const float xp0 = (float)xpc[s][h0 + lr];
        const float xp1 = (float)xpc[s][h0 + 16 + lr];
        i32x4 m0 = __builtin_amdgcn_mfma_i32_16x16x64_i8(qa0, wQ[0], zi, 0, 0, 0);
        i32x4 m1 = __builtin_amdgcn_mfma_i32_16x16x64_i8(qa1, wQ[1], zi, 0, 0, 0);
        i32x4 m2 = __builtin_amdgcn_mfma_i32_16x16x64_i8(qa2, wQ[2], zi, 0, 0, 0);
        i32x4 m3 = __builtin_amdgcn_mfma_i32_16x16x64_i8(qa3, wQ[3], zi, 0, 0, 0);
        i32x4 m4 = __builtin_amdgcn_mfma_i32_16x16x64_i8(qa0, wQ[4], zi, 0, 0, 0);
        i32x4 m5 = __builtin_amdgcn_mfma_i32_16x16x64_i8(qa1, wQ[5], zi, 0, 0, 0);
        i32x4 m6 = __builtin_amdgcn_mfma_i32_16x16x64_i8(qa2, wQ[6], zi, 0, 0, 0);
        i32x4 m7 = __builtin_amdgcn_mfma_i32_16x16x64_i8(qa3, wQ[7], zi, 0, 0, 0);
        int s0 = (m0[0] + m1[0]) + (m2[0] + m3[0]);   // exact i32 trees
        int s1 = (m4[0] + m5[0]) + (m6[0] + m7[0]);
        float y0 = (float)s0 * SCL + xp0;
        float y1 = (float)s1 * SCL + xp1;
        float e0 = __expf(2.f * y0);
        float hv0s = 1.f - 2.f * __builtin_amdgcn_rcpf(1.f + e0);   // tanh
        float e1 = __expf(2.f * y1);
        float hv1s = 1.f - 2.f * __builtin_amdgcn_rcpf(1.f + e1);

        // (5) critical write first: h-quant, then outs staging
        if (l < 16) {
          char* qn = qhb[(s & 1) ^ 1];
          qn[h0 + lr]      = (char)(int)rintf(hv0s * 127.f);
          qn[h0 + 16 + lr] = (char)(int)rintf(hv1s * 127.f);
          outs[s][h0 + lr]      = (_Float16)hv0s;
          outs[s][h0 + 16 + lr] = (_Float16)hv1s;
        }
        __syncthreads();
      }
      // finalize background group: 4 rows of next chunk's xp
      if (havenext) {
        const float bb = mt ? bias1 : bias0;
#pragma unroll
        for (int r = 0; r < 4; ++r)
          xpn[tt * 16 + g * 4 + r][h0 + mt * 16 + lr] = (_Float16)(pacc[r] + bb);
      }
    }
  }

  // ---- epilogue: flush last chunk's outs ----
#pragma unroll
  for (int k2 = 0; k2 < 8; ++k2) {
    const int m = k2 * 512 + tid;
    f16x4 v = ((const f16x4*)outs)[m];
    const int row = m >> 6;
    const int col = (m & 63) * 4;
    *(f32x4*)(io + base + (size_t)(T_ - CHUNK + row) * H_ + col) =
        f32x4{(float)v[0], (float)v[1], (float)v[2], (float)v[3]};
  }
}

extern "C" void kernel_launch(void* const* d_in, const int* in_sizes, int n_in,
                              void* d_out, int out_size, void* d_ws, size_t ws_size,
                              hipStream_t stream) {
  const float* x  = (const float*)d_in[0];
  const float* wx = (const float*)d_in[1];
  const float* wh = (const float*)d_in[2];
  const float* b  = (const float*)d_in[3];
  float* out = (float*)d_out;
  (void)d_ws; (void)ws_size;
  rnn_fused<<<B_, 512, 0, stream>>>(x, wx, wh, b, out);
}

// Round 19
// 232.266 us; speedup vs baseline: 1.0350x; 1.0350x over previous
//
#include <hip/hip_runtime.h>

#define B_ 256
#define T_ 512
#define I_ 256
#define H_ 256
#define CHUNK 64

typedef float    f32x4 __attribute__((ext_vector_type(4)));
typedef int      i32x4 __attribute__((ext_vector_type(4)));
typedef _Float16 f16x2 __attribute__((ext_vector_type(2)));
typedef _Float16 f16x4 __attribute__((ext_vector_type(4)));
typedef _Float16 f16x8 __attribute__((ext_vector_type(8)));

static __device__ __forceinline__ f16x8 cvt8(f32x4 a, f32x4 b) {
  return f16x8{(_Float16)a[0], (_Float16)a[1], (_Float16)a[2], (_Float16)a[3],
               (_Float16)b[0], (_Float16)b[1], (_Float16)b[2], (_Float16)b[3]};
}

// ---------------- fused RNN v12 (PROVEN 228.7us) — exact revert of round-17 ----------------
// r18 lesson: source-level tail reordering (v13) regressed 228.7->240.4; the compiler
// already schedules the step body optimally. This is the round-17 source verbatim.
// Structure: i8 16x16x64 recurrence (W x2032, h x127, i32 exact accum), f16 background
// xproj pipelined into the step slack, per-step flush interleave, chunked LDS staging.
__global__ __launch_bounds__(512) void rnn_fused(const float* __restrict__ x,
                                                 const float* __restrict__ wxf,
                                                 const float* __restrict__ whf,
                                                 const float* __restrict__ bias_g,
                                                 float* __restrict__ io) {
  __shared__ __align__(16) _Float16 xpsA[CHUNK][H_];  // 32KB  xp double-buffer A
  __shared__ __align__(16) _Float16 xpsB[CHUNK][H_];  // 32KB  xp double-buffer B
  __shared__ __align__(16) _Float16 outs[CHUNK][H_];  // 32KB  staged outputs (f16)
  __shared__ __align__(16) char     sx[32768];        // 32KB  swizzled x[64][256] f16
  __shared__ __align__(16) char     qhb[2][H_];       // 512B  h state, i8, double-buffered

  const int tid = threadIdx.x;
  const int l   = tid & 63;
  const int w   = tid >> 6;
  const int lr  = l & 15;
  const int g   = l >> 4;
  const int h0  = w * 32;
  const size_t base = (size_t)blockIdx.x * (size_t)(T_ * H_);

  // stationary W_x f16 frags (64 VGPR) + W_h i8 frags (32 VGPR)
  f16x8 xB[16];
  i32x4 wQ[8];                                        // [tile*4 + ks]
#pragma unroll
  for (int tile = 0; tile < 2; ++tile) {
#pragma unroll
    for (int kc = 0; kc < 8; ++kc) {
      const float* px = wxf + (size_t)(h0 + tile * 16 + lr) * I_ + kc * 32 + g * 8;
      xB[tile * 8 + kc] = cvt8(*(const f32x4*)px, *(const f32x4*)(px + 4));
    }
#pragma unroll
    for (int ks = 0; ks < 4; ++ks) {
      const float* ph = whf + (size_t)(h0 + tile * 16 + lr) * H_ + ks * 64 + g * 16;
      i32x4 q;
#pragma unroll
      for (int w4 = 0; w4 < 4; ++w4) {
        f32x4 vv = *(const f32x4*)(ph + w4 * 4);
        int word = 0;
#pragma unroll
        for (int j = 0; j < 4; ++j) {
          float sq = fminf(fmaxf(vv[j] * 2032.f, -127.f), 127.f);
          word |= (((int)rintf(sq)) & 255) << (8 * j);
        }
        q[w4] = word;
      }
      wQ[tile * 4 + ks] = q;
    }
  }
  const float bias0 = bias_g[h0 + lr];
  const float bias1 = bias_g[h0 + 16 + lr];
  if (tid < 128) ((int*)qhb)[tid] = 0;                // h_0 = 0 (both buffers)

  const f32x4 z4 = f32x4{0.f, 0.f, 0.f, 0.f};
  const i32x4 zi = i32x4{0, 0, 0, 0};
  const float SCL = 1.f / 258064.f;                   // 1/(2032*127)
  const int swzr = (lr & 7) << 4;

  // ---- prologue: stage x[chunk 0] ----
  {
    const f32x4* src = (const f32x4*)(x + base);
#pragma unroll
    for (int j = 0; j < 4; ++j) {
      const int ebase = j * 4096 + tid * 8;
      f32x4 p0 = src[j * 1024 + tid * 2];
      f32x4 p1 = src[j * 1024 + tid * 2 + 1];
      const int row = ebase >> 8;
      const int boff = ((ebase & 255) * 2) ^ ((row & 7) << 4);
      *(f16x8*)(sx + row * 512 + boff) = cvt8(p0, p1);
    }
  }
  __syncthreads();
  // ---- prologue: full phase-1b -> xpsA ----
#pragma unroll 1
  for (int tt = 0; tt < 4; ++tt) {
    f32x4 aE0 = z4, aO0 = z4, aE1 = z4, aO1 = z4;
    const char* rowp = sx + (tt * 16 + lr) * 512;
#pragma unroll
    for (int kc = 0; kc < 8; kc += 2) {
      f16x8 a0 = *(const f16x8*)(rowp + ((kc * 64 + g * 16) ^ swzr));
      f16x8 a1 = *(const f16x8*)(rowp + (((kc + 1) * 64 + g * 16) ^ swzr));
      aE0 = __builtin_amdgcn_mfma_f32_16x16x32_f16(a0, xB[kc],         aE0, 0, 0, 0);
      aE1 = __builtin_amdgcn_mfma_f32_16x16x32_f16(a0, xB[8 + kc],     aE1, 0, 0, 0);
      aO0 = __builtin_amdgcn_mfma_f32_16x16x32_f16(a1, xB[kc + 1],     aO0, 0, 0, 0);
      aO1 = __builtin_amdgcn_mfma_f32_16x16x32_f16(a1, xB[8 + kc + 1], aO1, 0, 0, 0);
    }
    f32x4 y0 = aE0 + aO0, y1 = aE1 + aO1;
#pragma unroll
    for (int r = 0; r < 4; ++r) {
      xpsA[tt * 16 + g * 4 + r][h0 + lr]      = (_Float16)(y0[r] + bias0);
      xpsA[tt * 16 + g * 4 + r][h0 + 16 + lr] = (_Float16)(y1[r] + bias1);
    }
  }
  __syncthreads();

  // ---- main chunk loop ----
#pragma unroll 1
  for (int c = 0; c < 8; ++c) {
    const int t0 = c * CHUNK;
    _Float16 (*xpc)[H_] = (c & 1) ? xpsB : xpsA;
    _Float16 (*xpn)[H_] = (c & 1) ? xpsA : xpsB;
    const bool havenext = (c < 7);
    const int tprev = t0 - CHUNK;

    // phase 1a: stage x[c+1]
    if (havenext) {
      const f32x4* src = (const f32x4*)(x + base + (size_t)(t0 + CHUNK) * I_);
#pragma unroll
      for (int j = 0; j < 4; ++j) {
        const int ebase = j * 4096 + tid * 8;
        f32x4 p0 = src[j * 1024 + tid * 2];
        f32x4 p1 = src[j * 1024 + tid * 2 + 1];
        const int row = ebase >> 8;
        const int boff = ((ebase & 255) * 2) ^ ((row & 7) << 4);
        *(f16x8*)(sx + row * 512 + boff) = cvt8(p0, p1);
      }
    }
    __syncthreads();

    // pre-loop flush slot: prev chunk's row 0
    if (c > 0 && tid < 64) {
      f16x4 v = *(const f16x4*)&outs[0][tid * 4];
      *(f32x4*)(io + base + (size_t)tprev * H_ + tid * 4) =
          f32x4{(float)v[0], (float)v[1], (float)v[2], (float)v[3]};
    }
    __syncthreads();

    // 64 steps, 8 groups of 8; unroll 2 keeps mt/xB indices static
#pragma unroll 2
    for (int sb = 0; sb < 8; ++sb) {
      const int tt = sb >> 1;
      const int mt = sb & 1;
      f32x4 pacc = z4;
#pragma unroll
      for (int si = 0; si < 8; ++si) {
        const int s = sb * 8 + si;

        // (a) flush slice: prev chunk row s+1
        if (c > 0 && s < 63 && tid < 64) {
          f16x4 v = *(const f16x4*)&outs[s + 1][tid * 4];
          *(f32x4*)(io + base + (size_t)(tprev + s + 1) * H_ + tid * 4) =
              f32x4{(float)v[0], (float)v[1], (float)v[2], (float)v[3]};
        }

        // (b) background xproj MFMA for next chunk (f16)
        if (havenext) {
          const char* rowp = sx + (tt * 16 + lr) * 512;
          f16x8 a = *(const f16x8*)(rowp + ((si * 64 + g * 16) ^ swzr));
          if (mt == 0)
            pacc = __builtin_amdgcn_mfma_f32_16x16x32_f16(a, xB[si],     pacc, 0, 0, 0);
          else
            pacc = __builtin_amdgcn_mfma_f32_16x16x32_f16(a, xB[8 + si], pacc, 0, 0, 0);
        }

        // (c) recurrence step s: i8 K=64, 8 MFMAs, broadcast-A trick
        const float xp0 = (float)xpc[s][h0 + lr];
        const float xp1 = (float)xpc[s][h0 + 16 + lr];
        const i32x4* qp = (const i32x4*)qhb[s & 1];
        i32x4 qa0 = qp[0 * 4 + g];                    // 4 distinct 16B addrs/wave
        i32x4 qa1 = qp[1 * 4 + g];
        i32x4 qa2 = qp[2 * 4 + g];
        i32x4 qa3 = qp[3 * 4 + g];
        i32x4 c0  = __builtin_amdgcn_mfma_i32_16x16x64_i8(qa0, wQ[0], zi, 0, 0, 0);
        i32x4 c0b = __builtin_amdgcn_mfma_i32_16x16x64_i8(qa2, wQ[2], zi, 0, 0, 0);
        i32x4 c1  = __builtin_amdgcn_mfma_i32_16x16x64_i8(qa0, wQ[4], zi, 0, 0, 0);
        i32x4 c1b = __builtin_amdgcn_mfma_i32_16x16x64_i8(qa2, wQ[6], zi, 0, 0, 0);
        c0  = __builtin_amdgcn_mfma_i32_16x16x64_i8(qa1, wQ[1], c0,  0, 0, 0);
        c0b = __builtin_amdgcn_mfma_i32_16x16x64_i8(qa3, wQ[3], c0b, 0, 0, 0);
        c1  = __builtin_amdgcn_mfma_i32_16x16x64_i8(qa1, wQ[5], c1,  0, 0, 0);
        c1b = __builtin_amdgcn_mfma_i32_16x16x64_i8(qa3, wQ[7], c1b, 0, 0, 0);
        float y0 = (float)(c0[0] + c0b[0]) * SCL + xp0;
        float y1 = (float)(c1[0] + c1b[0]) * SCL + xp1;
        float e0 = __expf(2.f * y0);
        float hv0s = 1.f - 2.f * __builtin_amdgcn_rcpf(1.f + e0);   // tanh
        float e1 = __expf(2.f * y1);
        float hv1s = 1.f - 2.f * __builtin_amdgcn_rcpf(1.f + e1);
        if (l < 16) {
          outs[s][h0 + lr]      = (_Float16)hv0s;
          outs[s][h0 + 16 + lr] = (_Float16)hv1s;
          char* qn = qhb[(s & 1) ^ 1];
          qn[h0 + lr]      = (char)(int)rintf(hv0s * 127.f);
          qn[h0 + 16 + lr] = (char)(int)rintf(hv1s * 127.f);
        }
        __syncthreads();
      }
      // finalize background group: 4 rows of next chunk's xp
      if (havenext) {
        const float bb = mt ? bias1 : bias0;
#pragma unroll
        for (int r = 0; r < 4; ++r)
          xpn[tt * 16 + g * 4 + r][h0 + mt * 16 + lr] = (_Float16)(pacc[r] + bb);
      }
    }
  }

  // ---- epilogue: flush last chunk's outs ----
#pragma unroll
  for (int k2 = 0; k2 < 8; ++k2) {
    const int m = k2 * 512 + tid;
    f16x4 v = ((const f16x4*)outs)[m];
    const int row = m >> 6;
    const int col = (m & 63) * 4;
    *(f32x4*)(io + base + (size_t)(T_ - CHUNK + row) * H_ + col) =
        f32x4{(float)v[0], (float)v[1], (float)v[2], (float)v[3]};
  }
}

extern "C" void kernel_launch(void* const* d_in, const int* in_sizes, int n_in,
                              void* d_out, int out_size, void* d_ws, size_t ws_size,
                              hipStream_t stream) {
  const float* x  = (const float*)d_in[0];
  const float* wx = (const float*)d_in[1];
  const float* wh = (const float*)d_in[2];
  const float* b  = (const float*)d_in[3];
  float* out = (float*)d_out;
  (void)d_ws; (void)ws_size;
  rnn_fused<<<B_, 512, 0, stream>>>(x, wx, wh, b, out);
}